// Round 6
// baseline (210.914 us; speedup 1.0000x reference)
//
#include <hip/hip_runtime.h>
#include <hip/hip_bf16.h>

#define B_ 16
#define N_ 1024
#define F_ 256
#define ALPHA 0.2f
#define NEG_BIG -9.0e15f
#define LOG2E 1.4426950408889634f

typedef float f4 __attribute__((ext_vector_type(4)));
typedef float f32x4 __attribute__((ext_vector_type(4)));
typedef short s16x8 __attribute__((ext_vector_type(8)));
typedef short s16x4 __attribute__((ext_vector_type(4)));

__device__ inline short f2bs(float x) {  // f32 -> bf16 bits via HW cvt (RNE)
    __hip_bfloat16 h = __float2bfloat16(x);
    return __builtin_bit_cast(short, h);
}

// ---------------------------------------------------------------------------
// K0: wa1[k] = sum_f W[k][f]*a1[f]; wa2 likewise. 64 blocks, 1 row per wave.
// ---------------------------------------------------------------------------
__global__ __launch_bounds__(256) void k_wa(const float* __restrict__ W,
                                            const float* __restrict__ a,
                                            float* __restrict__ wa) {
    const int t = threadIdx.x, lane = t & 63, w = t >> 6;
    const int row = blockIdx.x * 4 + w;
    const f4 wv = *(const f4*)(W + (size_t)row * F_ + lane * 4);
    const f4 a1 = *(const f4*)(a + lane * 4);
    const f4 a2 = *(const f4*)(a + F_ + lane * 4);
    float s1 = wv[0]*a1[0] + wv[1]*a1[1] + wv[2]*a1[2] + wv[3]*a1[3];
    float s2 = wv[0]*a2[0] + wv[1]*a2[1] + wv[2]*a2[2] + wv[3]*a2[3];
#pragma unroll
    for (int off = 32; off > 0; off >>= 1) {
        s1 += __shfl_xor(s1, off);
        s2 += __shfl_xor(s2, off);
    }
    if (lane == 0) { wa[row] = s1; wa[256 + row] = s2; }
}

// ---------------------------------------------------------------------------
// K0b: WTb[f][k] = bf16(W[k][f]).  16 blocks, LDS 64x65 transpose tile.
// 128 KB result stays L2-resident for k_gemm's B-fragment loads.
// ---------------------------------------------------------------------------
__global__ __launch_bounds__(256) void k_wt(const float* __restrict__ W,
                                            unsigned short* __restrict__ WTb) {
    __shared__ float tile[64][65];
    const int t = threadIdx.x;
    const int k0 = (blockIdx.x >> 2) * 64, f0 = (blockIdx.x & 3) * 64;
#pragma unroll
    for (int rep = 0; rep < 4; ++rep) {
        const int idx = rep * 256 + t;
        const int kr = idx >> 4, fc = (idx & 15) * 4;
        const f4 v = *(const f4*)(W + (size_t)(k0 + kr) * F_ + f0 + fc);
        tile[kr][fc] = v[0]; tile[kr][fc + 1] = v[1];
        tile[kr][fc + 2] = v[2]; tile[kr][fc + 3] = v[3];
    }
    __syncthreads();
#pragma unroll
    for (int rep = 0; rep < 4; ++rep) {
        const int idx = rep * 256 + t;
        const int fr = idx >> 4, kc = (idx & 15) * 4;
        s16x4 v;
        v[0] = f2bs(tile[kc][fr]);     v[1] = f2bs(tile[kc + 1][fr]);
        v[2] = f2bs(tile[kc + 2][fr]); v[3] = f2bs(tile[kc + 3][fr]);
        *(s16x4*)(WTb + (size_t)(f0 + fr) * F_ + k0 + kc) = v;
    }
}

// ---------------------------------------------------------------------------
// K1: WhT[b][f][m] (bf16) = transpose(h @ W).  LDS-free, barrier-free.
// Block = 32m x 256f, 4 waves = (ih x fh); wave = 16m x 128f, acc 8 f-tiles.
// A-fragment: per-lane contiguous 32B of own h row (cvt in regs).
// B-fragment: 16B from L2-resident WTb row (16 rows x 64B / instr, coalesced).
// ---------------------------------------------------------------------------
__global__ __launch_bounds__(256, 4) void k_gemm(const float* __restrict__ h,
                                                 const unsigned short* __restrict__ WTb,
                                                 unsigned short* __restrict__ WhT) {
    const int t = threadIdx.x, l = t & 63, w = t >> 6;
    const int ih = w >> 1, fh = w & 1;
    const int m0 = blockIdx.x * 32;
    const int li = l & 15, jg = l >> 4;
    const int mrow = m0 + ih * 16 + li;
    const float* hrow = h + (size_t)mrow * F_ + jg * 8;
    const unsigned short* bbase = WTb + (size_t)(fh * 128 + li) * F_ + jg * 8;
    f32x4 acc[8] = {};
#pragma unroll
    for (int kk = 0; kk < 8; ++kk) {
        const f4 lo = *(const f4*)(hrow + kk * 32);
        const f4 hi = *(const f4*)(hrow + kk * 32 + 4);
        s16x8 av;
        av[0]=f2bs(lo[0]); av[1]=f2bs(lo[1]); av[2]=f2bs(lo[2]); av[3]=f2bs(lo[3]);
        av[4]=f2bs(hi[0]); av[5]=f2bs(hi[1]); av[6]=f2bs(hi[2]); av[7]=f2bs(hi[3]);
#pragma unroll
        for (int ft = 0; ft < 8; ++ft) {
            const s16x8 bv = *(const s16x8*)(bbase + (size_t)ft * 16 * F_ + kk * 32);
            acc[ft] = __builtin_amdgcn_mfma_f32_16x16x32_bf16(av, bv, acc[ft], 0, 0, 0);
        }
    }
    // C layout (m89): col=lane&15 -> f, row=jg*4+q -> m (4 consecutive m / lane)
    const int bb = m0 >> 10;
    const int mb = (m0 & 1023) + ih * 16 + jg * 4;
#pragma unroll
    for (int ft = 0; ft < 8; ++ft) {
        const int fg = fh * 128 + ft * 16 + li;
        s16x4 v;
        v[0]=f2bs(acc[ft][0]); v[1]=f2bs(acc[ft][1]);
        v[2]=f2bs(acc[ft][2]); v[3]=f2bs(acc[ft][3]);
        *(s16x4*)(WhT + ((size_t)(bb * 256 + fg)) * 1024 + mb) = v;
    }
}

// ---------------------------------------------------------------------------
// K2: ei = (h@wa1)*log2e, ej = (h@wa2)*log2e. One wave per row.
// ---------------------------------------------------------------------------
__global__ __launch_bounds__(256) void k_e2(const float* __restrict__ h,
                                            const float* __restrict__ wa,
                                            float* __restrict__ ei,
                                            float* __restrict__ ej) {
    const int lane = threadIdx.x & 63;
    const int row = blockIdx.x * 4 + (threadIdx.x >> 6);
    const f4 hv = *(const f4*)(h + (size_t)row * F_ + lane * 4);
    const f4 w1 = *(const f4*)(wa + lane * 4);
    const f4 w2 = *(const f4*)(wa + 256 + lane * 4);
    float s1 = hv[0]*w1[0] + hv[1]*w1[1] + hv[2]*w1[2] + hv[3]*w1[3];
    float s2 = hv[0]*w2[0] + hv[1]*w2[1] + hv[2]*w2[2] + hv[3]*w2[3];
#pragma unroll
    for (int off = 32; off > 0; off >>= 1) {
        s1 += __shfl_xor(s1, off);
        s2 += __shfl_xor(s2, off);
    }
    if (lane == 0) { ei[row] = s1 * LOG2E; ej[row] = s2 * LOG2E; }
}

// ---------------------------------------------------------------------------
// K3: fused mask+leaky+online-softmax+PV(MFMA)+ELU — LDS-free, barrier-free.
// Wh[b] (512 KB bf16) is L2-resident (XCD swizzle: 2 batches/XCD); B-fragments
// load directly from L2 (16B/lane, 16 rows x 64B per instr — coalesced).
// Waves fully independent: 16 i-rows x 128 f each; softmax in-register with
// two shfl_xor; defer-max (THR=8*log2e); adj/ej prefetched one tile ahead.
// ---------------------------------------------------------------------------
__global__ __launch_bounds__(256, 4) void k_attn(const unsigned short* __restrict__ WhT,
                                                 const float* __restrict__ ei_g,
                                                 const float* __restrict__ ej_g,
                                                 const int* __restrict__ adj,
                                                 float* __restrict__ out) {
    const int id = blockIdx.x;
    const int xcd = id & 7, slot = id >> 3;           // 2 batches per XCD
    const int b = xcd * 2 + (slot >> 5);
    const int i0 = (slot & 31) * 32;

    const int t = threadIdx.x, l = t & 63, w = t >> 6;
    const int ih = w >> 1, fbase = (w & 1) * 128;
    const int li = l & 15, jg = l >> 4;
    const int irow = i0 + ih * 16 + li;

    const unsigned short* whb = WhT + (size_t)b * F_ * N_;
    const int* adjrow = adj + ((size_t)b * N_ + irow) * N_;
    const float* ejb = ej_g + b * N_;
    const float eival = ei_g[b * N_ + irow];

    // hoisted B-fragment row pointers (lane li -> f, jg -> k-slot)
    const unsigned short* bptr[8];
#pragma unroll
    for (int ft = 0; ft < 8; ++ft)
        bptr[ft] = whb + (size_t)(fbase + ft * 16 + li) * N_ + jg * 8;

    float m = NEG_BIG, ll = 0.f;
    f32x4 acc[8] = {};

    int4 adjc[4];
    f4 ejc[4];
#pragma unroll
    for (int q = 0; q < 4; ++q) {
        adjc[q] = *(const int4*)(adjrow + (q >> 1) * 32 + jg * 8 + (q & 1) * 4);
        ejc[q] = *(const f4*)(ejb + (q >> 1) * 32 + jg * 8 + (q & 1) * 4);
    }

    for (int s = 0; s < 16; ++s) {
        int4 adjn[4];
        f4 ejn[4];
        if (s < 15) {                                  // prefetch next tile
            const int j0n = (s + 1) * 64;
#pragma unroll
            for (int q = 0; q < 4; ++q) {
                adjn[q] = *(const int4*)(adjrow + j0n + (q >> 1) * 32 + jg * 8 + (q & 1) * 4);
                ejn[q] = *(const f4*)(ejb + j0n + (q >> 1) * 32 + jg * 8 + (q & 1) * 4);
            }
        }
#pragma unroll
        for (int sub = 0; sub < 2; ++sub) {
            const f4 ej0 = ejc[sub * 2], ej1 = ejc[sub * 2 + 1];
            const int4 a0 = adjc[sub * 2], a1 = adjc[sub * 2 + 1];
            float p[8];
            float tm = NEG_BIG;
#pragma unroll
            for (int e = 0; e < 8; ++e) {
                const float ejv = (e < 4) ? ej0[e] : ej1[e - 4];
                float sc = eival + ejv;
                sc = fmaxf(sc, ALPHA * sc);            // leaky (scale-commuted)
                const int ad = (e < 4) ? ((const int*)&a0)[e] : ((const int*)&a1)[e - 4];
                sc = ad > 0 ? sc : NEG_BIG;
                p[e] = sc;
                tm = fmaxf(tm, sc);
            }
            tm = fmaxf(tm, __shfl_xor(tm, 16));
            tm = fmaxf(tm, __shfl_xor(tm, 32));
            if (__any(tm > m + 11.5f)) {               // defer-max (8*log2e)
                const float mn = fmaxf(m, tm);
                const float fac = __builtin_amdgcn_exp2f(m - mn);
                m = mn;
                ll *= fac;
                float fr[4];
#pragma unroll
                for (int q = 0; q < 4; ++q) fr[q] = __shfl(fac, jg * 4 + q);
#pragma unroll
                for (int ft = 0; ft < 8; ++ft)
#pragma unroll
                    for (int q = 0; q < 4; ++q) acc[ft][q] *= fr[q];
            }
            float sum = 0.f;
            s16x8 afrag;
#pragma unroll
            for (int e = 0; e < 8; ++e) {
                const float pe = __builtin_amdgcn_exp2f(p[e] - m);
                afrag[e] = f2bs(pe);
                sum += pe;
            }
            sum += __shfl_xor(sum, 16);
            sum += __shfl_xor(sum, 32);
            ll += sum;
#pragma unroll
            for (int ft = 0; ft < 8; ++ft) {
                const s16x8 bv = *(const s16x8*)(bptr[ft] + s * 64 + sub * 32);
                acc[ft] = __builtin_amdgcn_mfma_f32_16x16x32_bf16(afrag, bv, acc[ft], 0, 0, 0);
            }
        }
        if (s < 15) {
#pragma unroll
            for (int q = 0; q < 4; ++q) { adjc[q] = adjn[q]; ejc[q] = ejn[q]; }
        }
    }

    // epilogue: normalize, ELU, store
    const float il = 1.f / ll;
    float inv[4];
#pragma unroll
    for (int q = 0; q < 4; ++q) inv[q] = __shfl(il, jg * 4 + q);
#pragma unroll
    for (int ft = 0; ft < 8; ++ft) {
#pragma unroll
        for (int q = 0; q < 4; ++q) {
            float v = acc[ft][q] * inv[q];
            v = v > 0.f ? v : __builtin_amdgcn_exp2f(v * LOG2E) - 1.f;
            out[((size_t)b * N_ + i0 + ih * 16 + jg * 4 + q) * F_ + fbase + ft * 16 + li] = v;
        }
    }
}

// ---------------------------------------------------------------------------
extern "C" void kernel_launch(void* const* d_in, const int* in_sizes, int n_in,
                              void* d_out, int out_size, void* d_ws, size_t ws_size,
                              hipStream_t stream) {
    const float* h = (const float*)d_in[0];
    const int* adj = (const int*)d_in[1];
    const float* W = (const float*)d_in[2];
    const float* a = (const float*)d_in[3];
    float* out = (float*)d_out;

    unsigned short* WhT = (unsigned short*)d_ws;          // 8 MB bf16 [b][f][m]
    float* wa = (float*)(WhT + (size_t)B_ * N_ * F_);     // 512 f32
    float* ei = wa + 512;                                 // 16384 f32
    float* ej = ei + (size_t)B_ * N_;                     // 16384 f32
    unsigned short* WTb = (unsigned short*)(ej + (size_t)B_ * N_);  // 64K bf16

    k_wa<<<64, 256, 0, stream>>>(W, a, wa);
    k_wt<<<16, 256, 0, stream>>>(W, WTb);
    k_gemm<<<512, 256, 0, stream>>>(h, WTb, WhT);
    k_e2<<<(B_ * N_) / 4, 256, 0, stream>>>(h, wa, ei, ej);
    k_attn<<<512, 256, 0, stream>>>(WhT, ei, ej, adj, out);
}

// Round 8
// 188.158 us; speedup vs baseline: 1.1209x; 1.1209x over previous
//
#include <hip/hip_runtime.h>
#include <hip/hip_bf16.h>

#define B_ 16
#define N_ 1024
#define F_ 256
#define ALPHA 0.2f
#define NEG_BIG -9.0e15f
#define LOG2E 1.4426950408889634f

typedef float f4 __attribute__((ext_vector_type(4)));
typedef float f32x4 __attribute__((ext_vector_type(4)));
typedef short s16x8 __attribute__((ext_vector_type(8)));
typedef short s16x4 __attribute__((ext_vector_type(4)));

__device__ inline short f2bs(float x) {
    __hip_bfloat16 h = __float2bfloat16(x);
    return __builtin_bit_cast(short, h);
}

// ---------------------------------------------------------------------------
// K_pre: role A (blocks 0..63): wa = [W@a1 ; W@a2]; role B (64..79): WTb[f][k]
// = bf16(W^T) via LDS transpose. 80 blocks total.
// ---------------------------------------------------------------------------
__global__ __launch_bounds__(256) void k_pre(const float* __restrict__ W,
                                             const float* __restrict__ a,
                                             float* __restrict__ wa,
                                             unsigned short* __restrict__ WTb) {
    const int t = threadIdx.x, lane = t & 63, w = t >> 6;
    if (blockIdx.x < 64) {
        const int row = blockIdx.x * 4 + w;
        const f4 wv = *(const f4*)(W + (size_t)row * F_ + lane * 4);
        const f4 a1 = *(const f4*)(a + lane * 4);
        const f4 a2 = *(const f4*)(a + F_ + lane * 4);
        float s1 = wv[0]*a1[0] + wv[1]*a1[1] + wv[2]*a1[2] + wv[3]*a1[3];
        float s2 = wv[0]*a2[0] + wv[1]*a2[1] + wv[2]*a2[2] + wv[3]*a2[3];
#pragma unroll
        for (int off = 32; off > 0; off >>= 1) {
            s1 += __shfl_xor(s1, off);
            s2 += __shfl_xor(s2, off);
        }
        if (lane == 0) { wa[row] = s1; wa[256 + row] = s2; }
    } else {
        __shared__ float tile[64][65];
        const int wb = blockIdx.x - 64;
        const int k0 = (wb >> 2) * 64, f0 = (wb & 3) * 64;
#pragma unroll
        for (int rep = 0; rep < 4; ++rep) {
            const int idx = rep * 256 + t;
            const int kr = idx >> 4, fc = (idx & 15) * 4;
            const f4 v = *(const f4*)(W + (size_t)(k0 + kr) * F_ + f0 + fc);
            tile[kr][fc] = v[0]; tile[kr][fc + 1] = v[1];
            tile[kr][fc + 2] = v[2]; tile[kr][fc + 3] = v[3];
        }
        __syncthreads();
#pragma unroll
        for (int rep = 0; rep < 4; ++rep) {
            const int idx = rep * 256 + t;
            const int fr = idx >> 4, kc = (idx & 15) * 4;
            s16x4 v;
            v[0] = f2bs(tile[kc][fr]);     v[1] = f2bs(tile[kc + 1][fr]);
            v[2] = f2bs(tile[kc + 2][fr]); v[3] = f2bs(tile[kc + 3][fr]);
            *(s16x4*)(WTb + (size_t)(f0 + fr) * F_ + k0 + kc) = v;
        }
    }
}

// ---------------------------------------------------------------------------
// K_big: three roles by block range (streams overlap on the device):
//  A (0..2047):   adj (64 MB) -> 1-bit mask (2 MB). Wave reads a full row
//                 (16 coalesced dword loads), 16 ballots -> 16 uint64 words.
//  B (2048..2559): Wh^T GEMM (LDS-free MFMA, WTb L2-resident).
//  C (2560..6655): ei/ej = (h@wa)*log2e, one wave per row.
// ---------------------------------------------------------------------------
__global__ __launch_bounds__(256, 4) void k_big(const float* __restrict__ h,
                                                const unsigned short* __restrict__ WTb,
                                                const float* __restrict__ wa,
                                                const int* __restrict__ adj,
                                                unsigned short* __restrict__ WhT,
                                                float* __restrict__ ei,
                                                float* __restrict__ ej,
                                                unsigned long long* __restrict__ mask) {
    const int bid = blockIdx.x;
    const int t = threadIdx.x, l = t & 63, w = t >> 6;
    if (bid < 2048) {                                     // ---- mask role
        const int gw = bid * 4 + w;
#pragma unroll
        for (int rr = 0; rr < 2; ++rr) {
            const int row = gw + rr * 8192;
            const int* ar = adj + (size_t)row * 1024;
            int v[16];
#pragma unroll
            for (int g = 0; g < 16; ++g) v[g] = ar[g * 64 + l];
            unsigned long long myw = 0;
#pragma unroll
            for (int g = 0; g < 16; ++g) {
                const unsigned long long bal = __ballot(v[g] > 0);
                if (l == g) myw = bal;
            }
            if (l < 16) mask[(size_t)row * 16 + l] = myw;
        }
    } else if (bid < 2560) {                              // ---- gemm role
        const int m0 = (bid - 2048) * 32;
        const int ih = w >> 1, fh = w & 1;
        const int li = l & 15, jg = l >> 4;
        const int mrow = m0 + ih * 16 + li;
        const float* hrow = h + (size_t)mrow * F_ + jg * 8;
        const unsigned short* bbase = WTb + (size_t)(fh * 128 + li) * F_ + jg * 8;
        f32x4 acc[8] = {};
#pragma unroll
        for (int kk = 0; kk < 8; ++kk) {
            const f4 lo = *(const f4*)(hrow + kk * 32);
            const f4 hi = *(const f4*)(hrow + kk * 32 + 4);
            s16x8 av;
            av[0]=f2bs(lo[0]); av[1]=f2bs(lo[1]); av[2]=f2bs(lo[2]); av[3]=f2bs(lo[3]);
            av[4]=f2bs(hi[0]); av[5]=f2bs(hi[1]); av[6]=f2bs(hi[2]); av[7]=f2bs(hi[3]);
#pragma unroll
            for (int ft = 0; ft < 8; ++ft) {
                const s16x8 bv = *(const s16x8*)(bbase + (size_t)ft * 16 * F_ + kk * 32);
                acc[ft] = __builtin_amdgcn_mfma_f32_16x16x32_bf16(av, bv, acc[ft], 0, 0, 0);
            }
        }
        const int bb = m0 >> 10;
        const int mb = (m0 & 1023) + ih * 16 + jg * 4;
#pragma unroll
        for (int ft = 0; ft < 8; ++ft) {
            const int fg = fh * 128 + ft * 16 + li;
            s16x4 v;
            v[0]=f2bs(acc[ft][0]); v[1]=f2bs(acc[ft][1]);
            v[2]=f2bs(acc[ft][2]); v[3]=f2bs(acc[ft][3]);
            *(s16x4*)(WhT + ((size_t)(bb * 256 + fg)) * 1024 + mb) = v;
        }
    } else {                                              // ---- e-vector role
        const int row = (bid - 2560) * 4 + w;
        const f4 hv = *(const f4*)(h + (size_t)row * F_ + l * 4);
        const f4 w1 = *(const f4*)(wa + l * 4);
        const f4 w2 = *(const f4*)(wa + 256 + l * 4);
        float s1 = hv[0]*w1[0] + hv[1]*w1[1] + hv[2]*w1[2] + hv[3]*w1[3];
        float s2 = hv[0]*w2[0] + hv[1]*w2[1] + hv[2]*w2[2] + hv[3]*w2[3];
#pragma unroll
        for (int off = 32; off > 0; off >>= 1) {
            s1 += __shfl_xor(s1, off);
            s2 += __shfl_xor(s2, off);
        }
        if (l == 0) { ei[row] = s1 * LOG2E; ej[row] = s2 * LOG2E; }
    }
}

// ---------------------------------------------------------------------------
// K_attn: fused mask+leaky+online-softmax+PV(MFMA)+ELU. LDS/barrier-free.
// Block = 32 i x 256 f; wave = 32 i x 64 f (f-disjoint -> no duplicated
// B-fragment loads). Wh[b] (512 KB) + mask (128 KB/b) L2-resident via XCD
// swizzle. Mask applied AFTER max (p = bit*exp2(sc-m)) -- exact, avoids
// per-element NEG_BIG select before the reduce. Defer-max THR = 8*log2e.
// ---------------------------------------------------------------------------
__global__ __launch_bounds__(256, 2) void k_attn(const unsigned short* __restrict__ WhT,
                                                 const float* __restrict__ ei_g,
                                                 const float* __restrict__ ej_g,
                                                 const unsigned long long* __restrict__ mask,
                                                 float* __restrict__ out) {
    const int id = blockIdx.x;
    const int xcd = id & 7, slot = id >> 3;               // 2 batches per XCD
    const int b = xcd * 2 + (slot >> 5);
    const int i0 = (slot & 31) * 32;

    const int t = threadIdx.x, l = t & 63, w = t >> 6;
    const int fbase = w * 64;
    const int li = l & 15, jg = l >> 4;

    const unsigned short* whb = WhT + (size_t)b * F_ * N_;
    const float* ejb = ej_g + b * N_;
    const float ei0 = ei_g[b * N_ + i0 + li];
    const float ei1 = ei_g[b * N_ + i0 + 16 + li];
    const unsigned long long* mrow0 = mask + (size_t)(b * N_ + i0 + li) * 16;
    const unsigned long long* mrow1 = mrow0 + 256;        // +16 rows

    const unsigned short* bptr[4];
#pragma unroll
    for (int ft = 0; ft < 4; ++ft)
        bptr[ft] = whb + (size_t)(fbase + ft * 16 + li) * N_ + jg * 8;

    float m0 = NEG_BIG, m1 = NEG_BIG, ll0 = 0.f, ll1 = 0.f;
    f32x4 acc0[4] = {}, acc1[4] = {};

    for (int s = 0; s < 16; ++s) {
        // issue all tile loads up front (mask 8B broadcast, ej, 8x16B Wh)
        const unsigned long long w0 = mrow0[s], w1 = mrow1[s];
        const int jb = s * 64 + jg * 8;
        const f4 ejA = *(const f4*)(ejb + jb);
        const f4 ejB = *(const f4*)(ejb + jb + 4);
        const f4 ejC = *(const f4*)(ejb + jb + 32);
        const f4 ejD = *(const f4*)(ejb + jb + 36);
        s16x8 bv0[4], bv1[4];
#pragma unroll
        for (int ft = 0; ft < 4; ++ft) {
            bv0[ft] = *(const s16x8*)(bptr[ft] + s * 64);
            bv1[ft] = *(const s16x8*)(bptr[ft] + s * 64 + 32);
        }
#pragma unroll
        for (int sub = 0; sub < 2; ++sub) {
            const f4 eja = sub ? ejC : ejA;
            const f4 ejbv = sub ? ejD : ejB;
            const unsigned int ms0 = (unsigned int)(w0 >> (sub * 32 + jg * 8));
            const unsigned int ms1 = (unsigned int)(w1 >> (sub * 32 + jg * 8));
            float p0[8], p1[8];
            float tm0 = NEG_BIG, tm1 = NEG_BIG;
#pragma unroll
            for (int e = 0; e < 8; ++e) {
                const float ejv = (e < 4) ? eja[e] : ejbv[e - 4];
                float s0 = ei0 + ejv;
                s0 = fmaxf(s0, ALPHA * s0);
                p0[e] = s0; tm0 = fmaxf(tm0, s0);
                float s1 = ei1 + ejv;
                s1 = fmaxf(s1, ALPHA * s1);
                p1[e] = s1; tm1 = fmaxf(tm1, s1);
            }
            tm0 = fmaxf(tm0, __shfl_xor(tm0, 16));
            tm0 = fmaxf(tm0, __shfl_xor(tm0, 32));
            tm1 = fmaxf(tm1, __shfl_xor(tm1, 16));
            tm1 = fmaxf(tm1, __shfl_xor(tm1, 32));
            if (__any(tm0 > m0 + 11.5f)) {                // defer-max row0
                const float mn = fmaxf(m0, tm0);
                const float fac = __builtin_amdgcn_exp2f(m0 - mn);
                m0 = mn; ll0 *= fac;
                float fr[4];
#pragma unroll
                for (int q = 0; q < 4; ++q) fr[q] = __shfl(fac, jg * 4 + q);
#pragma unroll
                for (int ft = 0; ft < 4; ++ft)
#pragma unroll
                    for (int q = 0; q < 4; ++q) acc0[ft][q] *= fr[q];
            }
            if (__any(tm1 > m1 + 11.5f)) {                // defer-max row1
                const float mn = fmaxf(m1, tm1);
                const float fac = __builtin_amdgcn_exp2f(m1 - mn);
                m1 = mn; ll1 *= fac;
                float fr[4];
#pragma unroll
                for (int q = 0; q < 4; ++q) fr[q] = __shfl(fac, jg * 4 + q);
#pragma unroll
                for (int ft = 0; ft < 4; ++ft)
#pragma unroll
                    for (int q = 0; q < 4; ++q) acc1[ft][q] *= fr[q];
            }
            float sum0 = 0.f, sum1 = 0.f;
            s16x8 af0, af1;
#pragma unroll
            for (int e = 0; e < 8; ++e) {
                const float b0 = (float)((ms0 >> e) & 1u);
                const float b1 = (float)((ms1 >> e) & 1u);
                const float pe0 = __builtin_amdgcn_exp2f(p0[e] - m0) * b0;
                const float pe1 = __builtin_amdgcn_exp2f(p1[e] - m1) * b1;
                af0[e] = f2bs(pe0); sum0 += pe0;
                af1[e] = f2bs(pe1); sum1 += pe1;
            }
            sum0 += __shfl_xor(sum0, 16); sum0 += __shfl_xor(sum0, 32);
            sum1 += __shfl_xor(sum1, 16); sum1 += __shfl_xor(sum1, 32);
            ll0 += sum0; ll1 += sum1;
            const s16x8* bv = sub ? bv1 : bv0;
#pragma unroll
            for (int ft = 0; ft < 4; ++ft) {
                acc0[ft] = __builtin_amdgcn_mfma_f32_16x16x32_bf16(af0, bv[ft], acc0[ft], 0, 0, 0);
                acc1[ft] = __builtin_amdgcn_mfma_f32_16x16x32_bf16(af1, bv[ft], acc1[ft], 0, 0, 0);
            }
        }
    }

    // epilogue: normalize, ELU, store (C: row = jg*4+q, col = li)
    const float il0 = 1.f / ll0, il1 = 1.f / ll1;
    float inv0[4], inv1[4];
#pragma unroll
    for (int q = 0; q < 4; ++q) {
        inv0[q] = __shfl(il0, jg * 4 + q);
        inv1[q] = __shfl(il1, jg * 4 + q);
    }
#pragma unroll
    for (int ft = 0; ft < 4; ++ft) {
#pragma unroll
        for (int q = 0; q < 4; ++q) {
            float v0 = acc0[ft][q] * inv0[q];
            v0 = v0 > 0.f ? v0 : __builtin_amdgcn_exp2f(v0 * LOG2E) - 1.f;
            out[((size_t)b * N_ + i0 + jg * 4 + q) * F_ + fbase + ft * 16 + li] = v0;
            float v1 = acc1[ft][q] * inv1[q];
            v1 = v1 > 0.f ? v1 : __builtin_amdgcn_exp2f(v1 * LOG2E) - 1.f;
            out[((size_t)b * N_ + i0 + 16 + jg * 4 + q) * F_ + fbase + ft * 16 + li] = v1;
        }
    }
}

// ---------------------------------------------------------------------------
extern "C" void kernel_launch(void* const* d_in, const int* in_sizes, int n_in,
                              void* d_out, int out_size, void* d_ws, size_t ws_size,
                              hipStream_t stream) {
    const float* h = (const float*)d_in[0];
    const int* adj = (const int*)d_in[1];
    const float* W = (const float*)d_in[2];
    const float* a = (const float*)d_in[3];
    float* out = (float*)d_out;

    unsigned short* WhT = (unsigned short*)d_ws;                   // 8 MB
    float* wa = (float*)(WhT + (size_t)B_ * N_ * F_);              // 512 f32
    float* ei = wa + 512;                                          // 16384
    float* ej = ei + (size_t)B_ * N_;                              // 16384
    unsigned short* WTb = (unsigned short*)(ej + (size_t)B_ * N_); // 64K ushort
    unsigned long long* mask = (unsigned long long*)(WTb + 65536); // 2 MB

    k_pre<<<80, 256, 0, stream>>>(W, a, wa, WTb);
    k_big<<<6656, 256, 0, stream>>>(h, WTb, wa, adj, WhT, ei, ej, mask);
    k_attn<<<512, 256, 0, stream>>>(WhT, ei, ej, mask, out);
}